// Round 7
// baseline (100.769 us; speedup 1.0000x reference)
//
#include <hip/hip_runtime.h>
#include <hip/hip_bf16.h>
#include <math.h>

#define BB 8
#define TT 4096
#define HD 64

typedef __attribute__((ext_vector_type(8))) short short8;
typedef __attribute__((ext_vector_type(4))) float f32x4;
typedef __attribute__((ext_vector_type(16))) float f32x16;
typedef __attribute__((ext_vector_type(2))) unsigned int uint2v;
typedef __attribute__((ext_vector_type(4))) unsigned int uint4v;

#define LOG2E 1.44269504088896f

__device__ __forceinline__ unsigned short bfbits(float f) {
    return __builtin_bit_cast(unsigned short, __float2bfloat16(f));
}
__device__ __forceinline__ unsigned pack_bf2(float a, float b) {
    return (unsigned)bfbits(a) | ((unsigned)bfbits(b) << 16);
}
__device__ __forceinline__ float bf2f(unsigned short u) {
    unsigned v = (unsigned)u << 16;
    return __builtin_bit_cast(float, v);
}
__device__ __forceinline__ short8 cvt8(float4 a, float4 b, float sc) {
    short8 s;
    s[0] = (short)bfbits(a.x * sc); s[1] = (short)bfbits(a.y * sc);
    s[2] = (short)bfbits(a.z * sc); s[3] = (short)bfbits(a.w * sc);
    s[4] = (short)bfbits(b.x * sc); s[5] = (short)bfbits(b.y * sc);
    s[6] = (short)bfbits(b.z * sc); s[7] = (short)bfbits(b.w * sc);
    return s;
}

// ---------------- Kernel 1: MFMA QKV projection ----------------
__global__ __launch_bounds__(256) void qkv_proj_mfma(
    const float* __restrict__ x,
    const float* __restrict__ Wk, const float* __restrict__ Wq, const float* __restrict__ Wv,
    unsigned short* __restrict__ qo, unsigned short* __restrict__ ko,
    unsigned short* __restrict__ vto)
{
    __shared__ short lds[20480];
    short* xls = lds;
    short* wls = lds + 8192;

    const int tid = threadIdx.x;
    const int l = tid & 63, w = tid >> 6;
    const int hi = l >> 5, c31 = l & 31;
    const long t0 = (long)blockIdx.x * 128;
    const int b = (int)(t0 >> 12);
    const int tl0 = (int)(t0 & 4095);

#pragma unroll
    for (int i = 0; i < 4; ++i) {
        int slot = tid + 256 * i;
        int row = slot >> 3, bl = slot & 7;
        const float* xp = x + (t0 + row) * 64 + 8 * bl;
        float4 a = *(const float4*)xp;
        float4 bq = *(const float4*)(xp + 4);
        *(short8*)&xls[row * 64 + 8 * (bl ^ (row & 7))] = cvt8(a, bq, 1.f);
    }
#pragma unroll
    for (int i = 0; i < 6; ++i) {
        int slot = tid + 256 * i;
        int row = slot >> 3, bl = slot & 7;
        const float* wp;
        float sc;
        if (row < 64)       { wp = Wq + row * 64;         sc = 0.125f * LOG2E; }
        else if (row < 128) { wp = Wk + (row - 64) * 64;  sc = 1.f; }
        else                { wp = Wv + (row - 128) * 64; sc = 1.f; }
        wp += 8 * bl;
        float4 a = *(const float4*)wp;
        float4 bq = *(const float4*)(wp + 4);
        *(short8*)&wls[row * 64 + 8 * (bl ^ (row & 7))] = cvt8(a, bq, sc);
    }
    __syncthreads();

    short8 xf[4];
#pragma unroll
    for (int ki = 0; ki < 4; ++ki) {
        int row = 32 * w + c31;
        xf[ki] = *(const short8*)&xls[row * 64 + 8 * ((2 * ki + hi) ^ (row & 7))];
    }
    f32x16 cqk[4] = {};
#pragma unroll
    for (int nt = 0; nt < 4; ++nt) {
#pragma unroll
        for (int ki = 0; ki < 4; ++ki) {
            int row = 32 * nt + c31;
            short8 wf = *(const short8*)&wls[row * 64 + 8 * ((2 * ki + hi) ^ (row & 7))];
            cqk[nt] = __builtin_amdgcn_mfma_f32_32x32x16_bf16(xf[ki], wf, cqk[nt], 0, 0, 0);
        }
    }
    f32x16 cv[2] = {};
#pragma unroll
    for (int rt = 0; rt < 2; ++rt) {
#pragma unroll
        for (int ki = 0; ki < 4; ++ki) {
            int row = 128 + 32 * rt + c31;
            short8 wf = *(const short8*)&wls[row * 64 + 8 * ((2 * ki + hi) ^ (row & 7))];
            cv[rt] = __builtin_amdgcn_mfma_f32_32x32x16_bf16(wf, xf[ki], cv[rt], 0, 0, 0);
        }
    }
#pragma unroll
    for (int rt = 0; rt < 2; ++rt) {
#pragma unroll
        for (int r = 0; r < 16; ++r) {
            int h = 32 * rt + (r & 3) + 8 * (r >> 2) + 4 * hi;
            vto[((long)b * 64 + h) * 4096 + tl0 + 32 * w + c31] = bfbits(cv[rt][r]);
        }
    }

    __syncthreads();
    short* cb = lds;
#pragma unroll
    for (int nt = 0; nt < 4; ++nt) {
#pragma unroll
        for (int r = 0; r < 16; ++r) {
            int trow = 32 * w + (r & 3) + 8 * (r >> 2) + 4 * hi;
            cb[trow * 136 + 32 * nt + c31] = (short)bfbits(cqk[nt][r]);
        }
    }
    __syncthreads();
    {
        int row = tid >> 1, seg = tid & 1;
        const short8* cp = (const short8*)&cb[row * 136 + seg * 64];
        unsigned short* dst = (seg == 0 ? qo : ko) + (t0 + row) * 64;
#pragma unroll
        for (int i = 0; i < 8; ++i) ((short8*)dst)[i] = cp[i];
    }
}

// ---------------- Kernel 2: MFMA flash attention ----------------
// 128-thr blocks (2 waves x 32 q-rows), chunk = 16 KV tiles (1024 s).
// Grid 1280 = 5 blocks/CU (LDS-capped). 2-phase global_load_lds pipeline,
// swapped QK^T (lane-local softmax, exp2 domain). Cross-half scalar
// reductions via __shfl_xor (round-5-proven); permlane32_swap only for the
// P redistribution (distinct operands — proven since round 3).
__global__ __launch_bounds__(128, 4) void attn_mfma(
    const unsigned short* __restrict__ qg,
    const unsigned short* __restrict__ kg,
    const unsigned short* __restrict__ vtg,
    unsigned short* __restrict__ Opart,
    float2* __restrict__ ml,
    float* __restrict__ outg)
{
    __shared__ short kls[2][4096];   // K[s][d] tiles (16B-block XOR swizzle via source)
    __shared__ short vls[2][4096];   // V^T[d][s] tiles

    const int tid = threadIdx.x;
    const int l = tid & 63, w = tid >> 6;     // w in {0,1}
    const int q = l & 31, hi = l >> 5;
    const int qs7 = q & 7;

    const int bid = blockIdx.x;
    const int b = bid & 7;
    const int j = bid >> 3;
    int qt = 0, ci = 0;
    {
        int acc = 0;
        for (int qq = 63; qq >= 0; --qq) {       // descending size (LPT)
            int nc = (qq >> 4) + 1;
            if (j < acc + nc) { qt = qq; ci = j - acc; break; }
            acc += nc;
        }
    }
    const int nch = (qt >> 4) + 1;
    int ntile = qt + 1 - 16 * ci;
    if (ntile > 16) ntile = 16;
    const int c0 = ci * 1024;

    const int q0w = qt * 64 + 32 * w;
    const int qr = q0w + q;
    const int diag = qt;                       // global index of diagonal KV tile

    const unsigned short* qb = qg + ((long)b * TT + qr) * HD;
    short8 qf[4];
#pragma unroll
    for (int ki = 0; ki < 4; ++ki) qf[ki] = *(const short8*)(qb + 16 * ki + 8 * hi);

    // LDS fragment byte offsets (identical for K and V^T reads), hoisted
    int ofs[2][4];
#pragma unroll
    for (int a = 0; a < 2; ++a)
#pragma unroll
        for (int i2 = 0; i2 < 4; ++i2)
            ofs[a][i2] = (32 * a + q) * 128 + 16 * ((2 * i2 + hi) ^ qs7);

    f32x16 oacc[2] = {};
    float m = -INFINITY, lsum = 0.f;

    const unsigned short* kbase = kg + (long)b * TT * HD;
    const unsigned short* vbase = vtg + (long)b * HD * TT;

    // staging: slot = 128c + 64w + lane; row = slot>>3, bl = slot&7.
    // LDS linear dest; global source pre-swizzled bl' = bl ^ (row&7).
    const int r8 = l >> 3;
    const int blsw = (l & 7) ^ r8;
    const long koff0 = (long)(8 * w + r8) * HD + 8 * blsw;
    const long voff0 = (long)(8 * w + r8) * TT + 8 * blsw;

#define STAGE(cur_, s_) do {                                                            \
    _Pragma("unroll")                                                                   \
    for (int c_ = 0; c_ < 4; ++c_) {                                                    \
        const unsigned short* kp_ = kbase + (long)(s_) * HD + koff0 + c_ * 1024;        \
        const unsigned short* vp_ = vbase + (s_) + voff0 + (long)c_ * 16 * TT;          \
        short* kd_ = &kls[cur_][c_ * 1024 + 512 * w];                                   \
        short* vd_ = &vls[cur_][c_ * 1024 + 512 * w];                                   \
        __builtin_amdgcn_global_load_lds((const __attribute__((address_space(1))) void*)kp_, \
                                         (__attribute__((address_space(3))) void*)kd_, 16, 0, 0); \
        __builtin_amdgcn_global_load_lds((const __attribute__((address_space(1))) void*)vp_, \
                                         (__attribute__((address_space(3))) void*)vd_, 16, 0, 0); \
    }                                                                                   \
} while (0)

    int cur = 0;
    STAGE(0, c0);

    for (int it = 0; it < ntile; ++it) {
        const int s0 = c0 + (it << 6);
        __syncthreads();                 // vmcnt(0)+barrier: buf[cur] ready
        if (it + 1 < ntile) STAGE(cur ^ 1, s0 + 64);

        const int gti = ci * 16 + it;
        const int nkt = (gti == diag && w == 0) ? 1 : 2;
        const short* kb_ = kls[cur];
        const short* vb_ = vls[cur];

        // ---- S^T = K Q^T ----
        f32x16 sacc[2] = {};
        __builtin_amdgcn_s_setprio(1);
#pragma unroll
        for (int kt = 0; kt < 2; ++kt) {
            if (kt < nkt) {
#pragma unroll
                for (int ki = 0; ki < 4; ++ki) {
                    short8 kf = *(const short8*)((const char*)kb_ + ofs[kt][ki]);
                    sacc[kt] = __builtin_amdgcn_mfma_f32_32x32x16_bf16(kf, qf[ki], sacc[kt], 0, 0, 0);
                }
            }
        }
        __builtin_amdgcn_s_setprio(0);

        // ---- causal mask (diag tile only) ----
        if (gti == diag) {
#pragma unroll
            for (int kt = 0; kt < 2; ++kt) {
                if (kt >= nkt) continue;
#pragma unroll
                for (int r = 0; r < 16; ++r) {
                    int kkg = s0 + 32 * kt + (r & 3) + 8 * (r >> 2) + 4 * hi;
                    if (kkg > qr) sacc[kt][r] = -INFINITY;
                }
            }
        }

        // ---- tree max (fmaxf pairs -> clang max3) + cross-half via shfl ----
        float t8[8];
#pragma unroll
        for (int r = 0; r < 8; ++r) {
            float a = fmaxf(sacc[0][r], sacc[0][r + 8]);
            if (nkt == 2) a = fmaxf(a, fmaxf(sacc[1][r], sacc[1][r + 8]));
            t8[r] = a;
        }
        float pmax = fmaxf(fmaxf(fmaxf(t8[0], t8[1]), fmaxf(t8[2], t8[3])),
                           fmaxf(fmaxf(t8[4], t8[5]), fmaxf(t8[6], t8[7])));
        pmax = fmaxf(pmax, __shfl_xor(pmax, 32, 64));
        if (__any(pmax > m)) {           // defer-rescale
            float mn = fmaxf(m, pmax);
            float fac = exp2f(m - mn);
            lsum *= fac;
            oacc[0] *= fac;
            oacc[1] *= fac;
            m = mn;
        }

        // ---- P = exp2(S - m), packed bf16 ----
        float rsum = 0.f;
        unsigned ulo[8], uhi[8];
#pragma unroll
        for (int kt = 0; kt < 2; ++kt) {
#pragma unroll
            for (int jj = 0; jj < 4; ++jj) {
                if (kt < nkt) {
                    float p0 = exp2f(sacc[kt][4 * jj + 0] - m);
                    float p1 = exp2f(sacc[kt][4 * jj + 1] - m);
                    float p2 = exp2f(sacc[kt][4 * jj + 2] - m);
                    float p3 = exp2f(sacc[kt][4 * jj + 3] - m);
                    rsum += (p0 + p1) + (p2 + p3);
                    ulo[4 * kt + jj] = pack_bf2(p0, p1);
                    uhi[4 * kt + jj] = pack_bf2(p2, p3);
                } else {
                    ulo[4 * kt + jj] = 0;
                    uhi[4 * kt + jj] = 0;
                }
            }
        }
        rsum += __shfl_xor(rsum, 32, 64);
        lsum += rsum;

        // ---- O^T += V^T P (P -> A-frag via permlane32_swap, distinct operands) ----
        const int nks = 2 * nkt;
#pragma unroll
        for (int ks = 0; ks < 4; ++ks) {
            if (ks >= nks) continue;
            uint2v rlo = __builtin_amdgcn_permlane32_swap(ulo[2 * ks], ulo[2 * ks + 1], false, false);
            uint2v rhi = __builtin_amdgcn_permlane32_swap(uhi[2 * ks], uhi[2 * ks + 1], false, false);
            uint4v paw;
            paw[0] = rlo[0]; paw[1] = rhi[0]; paw[2] = rlo[1]; paw[3] = rhi[1];
            short8 pa = __builtin_bit_cast(short8, paw);
            __builtin_amdgcn_s_setprio(1);
#pragma unroll
            for (int dt = 0; dt < 2; ++dt) {
                short8 vf = *(const short8*)((const char*)vb_ + ofs[dt][ks]);
                oacc[dt] = __builtin_amdgcn_mfma_f32_32x32x16_bf16(vf, pa, oacc[dt], 0, 0, 0);
            }
            __builtin_amdgcn_s_setprio(0);
        }
        cur ^= 1;
    }
#undef STAGE

    const int lr = 32 * w + q;
    if (nch == 1) {
        const float inv = 1.f / lsum;
        float* op = outg + ((long)b * TT + qr) * HD;
#pragma unroll
        for (int dt = 0; dt < 2; ++dt) {
#pragma unroll
            for (int jj = 0; jj < 4; ++jj) {
                f32x4 o4;
                o4[0] = oacc[dt][4 * jj + 0] * inv;
                o4[1] = oacc[dt][4 * jj + 1] * inv;
                o4[2] = oacc[dt][4 * jj + 2] * inv;
                o4[3] = oacc[dt][4 * jj + 3] * inv;
                *(f32x4*)(op + 32 * dt + 8 * jj + 4 * hi) = o4;
            }
        }
    } else {
        const float inv = lsum > 0.f ? 1.f / lsum : 0.f;
        unsigned short* po = Opart + ((long)(b * 160 + j) * 64 + lr) * 64;
#pragma unroll
        for (int dt = 0; dt < 2; ++dt) {
#pragma unroll
            for (int jj = 0; jj < 4; ++jj) {
                uint2v u;
                u[0] = pack_bf2(oacc[dt][4 * jj + 0] * inv, oacc[dt][4 * jj + 1] * inv);
                u[1] = pack_bf2(oacc[dt][4 * jj + 2] * inv, oacc[dt][4 * jj + 3] * inv);
                *(uint2v*)(po + 32 * dt + 8 * jj + 4 * hi) = u;
            }
        }
        ml[(long)(b * 160 + j) * 64 + lr] = make_float2(m, lsum);
    }
}

// ---------------- Kernel 3: combine partials (qt >= 16; exp2 domain) ----------------
__global__ __launch_bounds__(128) void combine(
    const unsigned short* __restrict__ Opart,
    const float2* __restrict__ ml,
    float* __restrict__ outg)
{
    const int bid = blockIdx.x;            // 384 = 8b x 48qt
    const int b = bid & 7, qt = 16 + (bid >> 3);
    const int nc = (qt >> 4) + 1;          // 2..4
    int jb = 0;
    for (int qq = 63; qq > qt; --qq) jb += (qq >> 4) + 1;

    const int tid = threadIdx.x;
    const int row = tid >> 1, dh = (tid & 1) * 32;
    const long base = (long)(b * 160 + jb) * 64 + row;

    float mv[4], lv[4], M = -INFINITY;
#pragma unroll
    for (int c = 0; c < 4; ++c) {
        mv[c] = -INFINITY; lv[c] = 0.f;
        if (c < nc) {
            float2 t = ml[base + (long)c * 64];
            mv[c] = t.x; lv[c] = t.y;
            M = fmaxf(M, mv[c]);
        }
    }
    float L = 0.f, wt[4];
#pragma unroll
    for (int c = 0; c < 4; ++c) {
        wt[c] = (c < nc) ? lv[c] * exp2f(mv[c] - M) : 0.f;
        L += wt[c];
    }
    float acc[32];
#pragma unroll
    for (int i = 0; i < 32; ++i) acc[i] = 0.f;
#pragma unroll
    for (int c = 0; c < 4; ++c) {
        if (c < nc && wt[c] > 0.f) {
            const short8* op = (const short8*)(Opart + (base + (long)c * 64) * 64 + dh);
#pragma unroll
            for (int i = 0; i < 4; ++i) {
                short8 v = op[i];
#pragma unroll
                for (int e = 0; e < 8; ++e)
                    acc[8 * i + e] += wt[c] * bf2f((unsigned short)v[e]);
            }
        }
    }
    const float invL = 1.f / L;
    float* dst = outg + ((long)b * TT + qt * 64 + row) * HD + dh;
#pragma unroll
    for (int i = 0; i < 8; ++i) {
        f32x4 o;
        o[0] = acc[4 * i + 0] * invL; o[1] = acc[4 * i + 1] * invL;
        o[2] = acc[4 * i + 2] * invL; o[3] = acc[4 * i + 3] * invL;
        *(f32x4*)(dst + 4 * i) = o;
    }
}

extern "C" void kernel_launch(void* const* d_in, const int* in_sizes, int n_in,
                              void* d_out, int out_size, void* d_ws, size_t ws_size,
                              hipStream_t stream) {
    const float* x  = (const float*)d_in[0];
    const float* Wk = (const float*)d_in[1];
    const float* Wq = (const float*)d_in[2];
    const float* Wv = (const float*)d_in[3];
    float* out = (float*)d_out;

    const long N = (long)BB * TT * HD;
    unsigned short* q16 = (unsigned short*)d_ws;
    unsigned short* k16 = q16 + N;
    unsigned short* vt16 = k16 + N;
    unsigned short* Opart = (unsigned short*)((char*)d_ws + 12 * 1024 * 1024);  // 10.5 MB
    float2* mlp = (float2*)((char*)d_ws + 23068672);                            // 0.66 MB

    qkv_proj_mfma<<<BB * TT / 128, 256, 0, stream>>>(x, Wk, Wq, Wv, q16, k16, vt16);
    attn_mfma<<<8 * 160, 128, 0, stream>>>(q16, k16, vt16, Opart, mlp, out);
    combine<<<8 * 48, 128, 0, stream>>>(Opart, mlp, out);
}

// Round 8
// 80.378 us; speedup vs baseline: 1.2537x; 1.2537x over previous
//
#include <hip/hip_runtime.h>
#include <hip/hip_bf16.h>
#include <math.h>

#define BB 8
#define TT 4096
#define HD 64

typedef __attribute__((ext_vector_type(8))) short short8;
typedef __attribute__((ext_vector_type(4))) float f32x4;
typedef __attribute__((ext_vector_type(16))) float f32x16;
typedef __attribute__((ext_vector_type(2))) unsigned int uint2v;
typedef __attribute__((ext_vector_type(4))) unsigned int uint4v;

#define LOG2E 1.44269504088896f

__device__ __forceinline__ unsigned short bfbits(float f) {
    return __builtin_bit_cast(unsigned short, __float2bfloat16(f));
}
__device__ __forceinline__ unsigned pack_bf2(float a, float b) {
    return (unsigned)bfbits(a) | ((unsigned)bfbits(b) << 16);
}
__device__ __forceinline__ float bf2f(unsigned short u) {
    unsigned v = (unsigned)u << 16;
    return __builtin_bit_cast(float, v);
}
__device__ __forceinline__ short8 cvt8(float4 a, float4 b, float sc) {
    short8 s;
    s[0] = (short)bfbits(a.x * sc); s[1] = (short)bfbits(a.y * sc);
    s[2] = (short)bfbits(a.z * sc); s[3] = (short)bfbits(a.w * sc);
    s[4] = (short)bfbits(b.x * sc); s[5] = (short)bfbits(b.y * sc);
    s[6] = (short)bfbits(b.z * sc); s[7] = (short)bfbits(b.w * sc);
    return s;
}

// ---------------- Kernel 1: MFMA QKV projection (unchanged, proven) ----------------
__global__ __launch_bounds__(256) void qkv_proj_mfma(
    const float* __restrict__ x,
    const float* __restrict__ Wk, const float* __restrict__ Wq, const float* __restrict__ Wv,
    unsigned short* __restrict__ qo, unsigned short* __restrict__ ko,
    unsigned short* __restrict__ vto)
{
    __shared__ short lds[20480];
    short* xls = lds;
    short* wls = lds + 8192;

    const int tid = threadIdx.x;
    const int l = tid & 63, w = tid >> 6;
    const int hi = l >> 5, c31 = l & 31;
    const long t0 = (long)blockIdx.x * 128;
    const int b = (int)(t0 >> 12);
    const int tl0 = (int)(t0 & 4095);

#pragma unroll
    for (int i = 0; i < 4; ++i) {
        int slot = tid + 256 * i;
        int row = slot >> 3, bl = slot & 7;
        const float* xp = x + (t0 + row) * 64 + 8 * bl;
        float4 a = *(const float4*)xp;
        float4 bq = *(const float4*)(xp + 4);
        *(short8*)&xls[row * 64 + 8 * (bl ^ (row & 7))] = cvt8(a, bq, 1.f);
    }
#pragma unroll
    for (int i = 0; i < 6; ++i) {
        int slot = tid + 256 * i;
        int row = slot >> 3, bl = slot & 7;
        const float* wp;
        float sc;
        if (row < 64)       { wp = Wq + row * 64;         sc = 0.125f * LOG2E; }
        else if (row < 128) { wp = Wk + (row - 64) * 64;  sc = 1.f; }
        else                { wp = Wv + (row - 128) * 64; sc = 1.f; }
        wp += 8 * bl;
        float4 a = *(const float4*)wp;
        float4 bq = *(const float4*)(wp + 4);
        *(short8*)&wls[row * 64 + 8 * (bl ^ (row & 7))] = cvt8(a, bq, sc);
    }
    __syncthreads();

    short8 xf[4];
#pragma unroll
    for (int ki = 0; ki < 4; ++ki) {
        int row = 32 * w + c31;
        xf[ki] = *(const short8*)&xls[row * 64 + 8 * ((2 * ki + hi) ^ (row & 7))];
    }
    f32x16 cqk[4] = {};
#pragma unroll
    for (int nt = 0; nt < 4; ++nt) {
#pragma unroll
        for (int ki = 0; ki < 4; ++ki) {
            int row = 32 * nt + c31;
            short8 wf = *(const short8*)&wls[row * 64 + 8 * ((2 * ki + hi) ^ (row & 7))];
            cqk[nt] = __builtin_amdgcn_mfma_f32_32x32x16_bf16(xf[ki], wf, cqk[nt], 0, 0, 0);
        }
    }
    f32x16 cv[2] = {};
#pragma unroll
    for (int rt = 0; rt < 2; ++rt) {
#pragma unroll
        for (int ki = 0; ki < 4; ++ki) {
            int row = 128 + 32 * rt + c31;
            short8 wf = *(const short8*)&wls[row * 64 + 8 * ((2 * ki + hi) ^ (row & 7))];
            cv[rt] = __builtin_amdgcn_mfma_f32_32x32x16_bf16(wf, xf[ki], cv[rt], 0, 0, 0);
        }
    }
#pragma unroll
    for (int rt = 0; rt < 2; ++rt) {
#pragma unroll
        for (int r = 0; r < 16; ++r) {
            int h = 32 * rt + (r & 3) + 8 * (r >> 2) + 4 * hi;
            vto[((long)b * 64 + h) * 4096 + tl0 + 32 * w + c31] = bfbits(cv[rt][r]);
        }
    }

    __syncthreads();
    short* cb = lds;
#pragma unroll
    for (int nt = 0; nt < 4; ++nt) {
#pragma unroll
        for (int r = 0; r < 16; ++r) {
            int trow = 32 * w + (r & 3) + 8 * (r >> 2) + 4 * hi;
            cb[trow * 136 + 32 * nt + c31] = (short)bfbits(cqk[nt][r]);
        }
    }
    __syncthreads();
    {
        int row = tid >> 1, seg = tid & 1;
        const short8* cp = (const short8*)&cb[row * 136 + seg * 64];
        unsigned short* dst = (seg == 0 ? qo : ko) + (t0 + row) * 64;
#pragma unroll
        for (int i = 0; i < 8; ++i) ((short8*)dst)[i] = cp[i];
    }
}

// ---------------- Kernel 2: MFMA flash attention, 3-buffer counted-vmcnt ----------------
// Round-5 geometry: 256 thr = 4 waves x 32 q-rows (128-row q-block), chunk = 16
// KV tiles, grid 640 (2.5 blocks/CU; LDS 48KB caps at 3). Pipeline (T3/T4):
// per tile {vmcnt(4|0); s_barrier; sched_barrier; issue STAGE(t+2); compute t}.
// Loads get 2 compute phases to land; barrier no longer drains vmcnt to 0.
__global__ __launch_bounds__(256, 3) void attn_mfma(
    const unsigned short* __restrict__ qg,
    const unsigned short* __restrict__ kg,
    const unsigned short* __restrict__ vtg,
    unsigned short* __restrict__ Opart,
    float2* __restrict__ ml,
    float* __restrict__ outg)
{
    __shared__ short kls[3][4096];   // K[s][d] tiles (16B-block XOR swizzle via source)
    __shared__ short vls[3][4096];   // V^T[d][s] tiles

    const int tid = threadIdx.x;
    const int l = tid & 63, w = tid >> 6;     // w in {0..3}
    const int q = l & 31, hi = l >> 5;
    const int qs7 = q & 7;

    const int bid = blockIdx.x;
    const int b = bid & 7;
    const int j = bid >> 3;
    int qt = 0, ci = 0;
    {
        int acc = 0;
        for (int qq = 31; qq >= 0; --qq) {       // descending size (LPT)
            int nc = (2 * qq + 17) >> 4;
            if (j < acc + nc) { qt = qq; ci = j - acc; break; }
            acc += nc;
        }
    }
    const int nch = (2 * qt + 17) >> 4;
    int ntile = 2 * qt + 2 - 16 * ci;
    if (ntile > 16) ntile = 16;
    const int c0 = ci * 1024;

    const int q0w = qt * 128 + 32 * w;
    const int qr = q0w + q;
    const int lastg = (q0w + 31) >> 6;         // wave's diagonal KV tile (global idx)

    const unsigned short* qb = qg + ((long)b * TT + qr) * HD;
    short8 qf[4];
#pragma unroll
    for (int ki = 0; ki < 4; ++ki) qf[ki] = *(const short8*)(qb + 16 * ki + 8 * hi);

    // hoisted LDS fragment byte offsets (same for K and V^T reads)
    int ofs[2][4];
#pragma unroll
    for (int a = 0; a < 2; ++a)
#pragma unroll
        for (int i2 = 0; i2 < 4; ++i2)
            ofs[a][i2] = (32 * a + q) * 128 + 16 * ((2 * i2 + hi) ^ qs7);

    f32x16 oacc[2] = {};
    float m = -INFINITY, lsum = 0.f;

    const unsigned short* kbase = kg + (long)b * TT * HD;
    const unsigned short* vbase = vtg + (long)b * HD * TT;

    // staging: slot = 256c + tid; row = slot>>3 (= 32c + 8w + r8), bl = slot&7.
    // LDS linear dest (wave-uniform base + lane*16); global src pre-swizzled.
    const int r8 = l >> 3;
    const int blsw = (l & 7) ^ r8;
    const long koff0 = (long)(8 * w + r8) * HD + 8 * blsw;
    const long voff0 = (long)(8 * w + r8) * TT + 8 * blsw;

#define STAGE(buf_, s_) do {                                                            \
    _Pragma("unroll")                                                                   \
    for (int c_ = 0; c_ < 2; ++c_) {                                                    \
        const unsigned short* kp_ = kbase + (long)(s_) * HD + koff0 + (long)c_ * 32 * HD; \
        const unsigned short* vp_ = vbase + (s_) + voff0 + (long)c_ * 32 * TT;          \
        short* kd_ = &kls[buf_][2048 * c_ + 512 * w];                                   \
        short* vd_ = &vls[buf_][2048 * c_ + 512 * w];                                   \
        __builtin_amdgcn_global_load_lds((const __attribute__((address_space(1))) void*)kp_, \
                                         (__attribute__((address_space(3))) void*)kd_, 16, 0, 0); \
        __builtin_amdgcn_global_load_lds((const __attribute__((address_space(1))) void*)vp_, \
                                         (__attribute__((address_space(3))) void*)vd_, 16, 0, 0); \
    }                                                                                   \
} while (0)

    // prologue: fill buffers 0 and 1 (4 loads each per thread)
    STAGE(0, c0);
    if (ntile > 1) STAGE(1, c0 + 64);

    int cur = 0, nxt2 = 2;                     // buf indices: current, current+2 (mod 3)
    for (int it = 0; it < ntile; ++it) {
        const int s0 = c0 + (it << 6);
        // counted drain: my 4 oldest loads (tile it) done; tile it+1's may fly.
        if (it + 1 < ntile) asm volatile("s_waitcnt vmcnt(4)" ::: "memory");
        else                asm volatile("s_waitcnt vmcnt(0)" ::: "memory");
        __builtin_amdgcn_s_barrier();          // all waves' tile-it loads visible
        __builtin_amdgcn_sched_barrier(0);     // pin: nothing crosses the barrier
        if (it + 2 < ntile) STAGE(nxt2, s0 + 128);

        if (s0 <= q0w + 31) {
            const int gti = ci * 16 + it;
            const int nkt = (gti == lastg && (w & 1) == 0) ? 1 : 2;
            const short* kb_ = kls[cur];
            const short* vb_ = vls[cur];

            // ---- S^T = K Q^T ----
            f32x16 sacc[2] = {};
            __builtin_amdgcn_s_setprio(1);
#pragma unroll
            for (int kt = 0; kt < 2; ++kt) {
                if (kt < nkt) {
#pragma unroll
                    for (int ki = 0; ki < 4; ++ki) {
                        short8 kf = *(const short8*)((const char*)kb_ + ofs[kt][ki]);
                        sacc[kt] = __builtin_amdgcn_mfma_f32_32x32x16_bf16(kf, qf[ki], sacc[kt], 0, 0, 0);
                    }
                }
            }
            __builtin_amdgcn_s_setprio(0);

            // ---- causal mask (diag tile only) ----
            if (gti == lastg) {
#pragma unroll
                for (int kt = 0; kt < 2; ++kt) {
                    if (kt >= nkt) continue;
#pragma unroll
                    for (int r = 0; r < 16; ++r) {
                        int kkg = s0 + 32 * kt + (r & 3) + 8 * (r >> 2) + 4 * hi;
                        if (kkg > qr) sacc[kt][r] = -INFINITY;
                    }
                }
            }

            // ---- tree max + cross-half shfl ----
            float t8[8];
#pragma unroll
            for (int r = 0; r < 8; ++r) {
                float a = fmaxf(sacc[0][r], sacc[0][r + 8]);
                if (nkt == 2) a = fmaxf(a, fmaxf(sacc[1][r], sacc[1][r + 8]));
                t8[r] = a;
            }
            float pmax = fmaxf(fmaxf(fmaxf(t8[0], t8[1]), fmaxf(t8[2], t8[3])),
                               fmaxf(fmaxf(t8[4], t8[5]), fmaxf(t8[6], t8[7])));
            pmax = fmaxf(pmax, __shfl_xor(pmax, 32, 64));
            if (__any(pmax > m)) {             // defer-rescale
                float mn = fmaxf(m, pmax);
                float fac = exp2f(m - mn);
                lsum *= fac;
                oacc[0] *= fac;
                oacc[1] *= fac;
                m = mn;
            }

            // ---- P = exp2(S - m), packed bf16 ----
            float rsum = 0.f;
            unsigned ulo[8], uhi[8];
#pragma unroll
            for (int kt = 0; kt < 2; ++kt) {
#pragma unroll
                for (int jj = 0; jj < 4; ++jj) {
                    if (kt < nkt) {
                        float p0 = exp2f(sacc[kt][4 * jj + 0] - m);
                        float p1 = exp2f(sacc[kt][4 * jj + 1] - m);
                        float p2 = exp2f(sacc[kt][4 * jj + 2] - m);
                        float p3 = exp2f(sacc[kt][4 * jj + 3] - m);
                        rsum += (p0 + p1) + (p2 + p3);
                        ulo[4 * kt + jj] = pack_bf2(p0, p1);
                        uhi[4 * kt + jj] = pack_bf2(p2, p3);
                    } else {
                        ulo[4 * kt + jj] = 0;
                        uhi[4 * kt + jj] = 0;
                    }
                }
            }
            rsum += __shfl_xor(rsum, 32, 64);
            lsum += rsum;

            // ---- O^T += V^T P (P -> A-frag via permlane32_swap) ----
            const int nks = 2 * nkt;
#pragma unroll
            for (int ks = 0; ks < 4; ++ks) {
                if (ks >= nks) continue;
                uint2v rlo = __builtin_amdgcn_permlane32_swap(ulo[2 * ks], ulo[2 * ks + 1], false, false);
                uint2v rhi = __builtin_amdgcn_permlane32_swap(uhi[2 * ks], uhi[2 * ks + 1], false, false);
                uint4v paw;
                paw[0] = rlo[0]; paw[1] = rhi[0]; paw[2] = rlo[1]; paw[3] = rhi[1];
                short8 pa = __builtin_bit_cast(short8, paw);
                __builtin_amdgcn_s_setprio(1);
#pragma unroll
                for (int dt = 0; dt < 2; ++dt) {
                    short8 vf = *(const short8*)((const char*)vb_ + ofs[dt][ks]);
                    oacc[dt] = __builtin_amdgcn_mfma_f32_32x32x16_bf16(vf, pa, oacc[dt], 0, 0, 0);
                }
                __builtin_amdgcn_s_setprio(0);
            }
        }
        cur = (cur == 2) ? 0 : cur + 1;
        nxt2 = (nxt2 == 2) ? 0 : nxt2 + 1;
    }
#undef STAGE

    const int lr = 32 * w + q;
    if (nch == 1) {
        const float inv = 1.f / lsum;
        float* op = outg + ((long)b * TT + qr) * HD;
#pragma unroll
        for (int dt = 0; dt < 2; ++dt) {
#pragma unroll
            for (int jj = 0; jj < 4; ++jj) {
                f32x4 o4;
                o4[0] = oacc[dt][4 * jj + 0] * inv;
                o4[1] = oacc[dt][4 * jj + 1] * inv;
                o4[2] = oacc[dt][4 * jj + 2] * inv;
                o4[3] = oacc[dt][4 * jj + 3] * inv;
                *(f32x4*)(op + 32 * dt + 8 * jj + 4 * hi) = o4;
            }
        }
    } else {
        const float inv = lsum > 0.f ? 1.f / lsum : 0.f;
        unsigned short* po = Opart + ((long)(b * 80 + j) * 128 + lr) * 64;
#pragma unroll
        for (int dt = 0; dt < 2; ++dt) {
#pragma unroll
            for (int jj = 0; jj < 4; ++jj) {
                uint2v u;
                u[0] = pack_bf2(oacc[dt][4 * jj + 0] * inv, oacc[dt][4 * jj + 1] * inv);
                u[1] = pack_bf2(oacc[dt][4 * jj + 2] * inv, oacc[dt][4 * jj + 3] * inv);
                *(uint2v*)(po + 32 * dt + 8 * jj + 4 * hi) = u;
            }
        }
        ml[(long)(b * 80 + j) * 128 + lr] = make_float2(m, lsum);
    }
}

// ---------------- Kernel 3: combine partials (qt >= 8; exp2 domain) ----------------
__global__ __launch_bounds__(256) void combine(
    const unsigned short* __restrict__ Opart,
    const float2* __restrict__ ml,
    float* __restrict__ outg)
{
    const int bid = blockIdx.x;            // 192 = 8b x 24qt
    const int b = bid & 7, qt = 8 + (bid >> 3);
    const int nc = (2 * qt + 17) >> 4;     // 2..4
    int jb = 0;
    for (int qq = 31; qq > qt; --qq) jb += (2 * qq + 17) >> 4;

    const int tid = threadIdx.x;
    const int row = tid >> 1, dh = (tid & 1) * 32;
    const long base = (long)(b * 80 + jb) * 128 + row;

    float mv[4], lv[4], M = -INFINITY;
#pragma unroll
    for (int c = 0; c < 4; ++c) {
        mv[c] = -INFINITY; lv[c] = 0.f;
        if (c < nc) {
            float2 t = ml[base + (long)c * 128];
            mv[c] = t.x; lv[c] = t.y;
            M = fmaxf(M, mv[c]);
        }
    }
    float L = 0.f, wt[4];
#pragma unroll
    for (int c = 0; c < 4; ++c) {
        wt[c] = (c < nc) ? lv[c] * exp2f(mv[c] - M) : 0.f;
        L += wt[c];
    }
    float acc[32];
#pragma unroll
    for (int i = 0; i < 32; ++i) acc[i] = 0.f;
#pragma unroll
    for (int c = 0; c < 4; ++c) {
        if (c < nc && wt[c] > 0.f) {
            const short8* op = (const short8*)(Opart + (base + (long)c * 128) * 64 + dh);
#pragma unroll
            for (int i = 0; i < 4; ++i) {
                short8 v = op[i];
#pragma unroll
                for (int e = 0; e < 8; ++e)
                    acc[8 * i + e] += wt[c] * bf2f((unsigned short)v[e]);
            }
        }
    }
    const float invL = 1.f / L;
    float* dst = outg + ((long)b * TT + qt * 128 + row) * HD + dh;
#pragma unroll
    for (int i = 0; i < 8; ++i) {
        f32x4 o;
        o[0] = acc[4 * i + 0] * invL; o[1] = acc[4 * i + 1] * invL;
        o[2] = acc[4 * i + 2] * invL; o[3] = acc[4 * i + 3] * invL;
        *(f32x4*)(dst + 4 * i) = o;
    }
}

extern "C" void kernel_launch(void* const* d_in, const int* in_sizes, int n_in,
                              void* d_out, int out_size, void* d_ws, size_t ws_size,
                              hipStream_t stream) {
    const float* x  = (const float*)d_in[0];
    const float* Wk = (const float*)d_in[1];
    const float* Wq = (const float*)d_in[2];
    const float* Wv = (const float*)d_in[3];
    float* out = (float*)d_out;

    const long N = (long)BB * TT * HD;
    unsigned short* q16 = (unsigned short*)d_ws;
    unsigned short* k16 = q16 + N;
    unsigned short* vt16 = k16 + N;
    unsigned short* Opart = (unsigned short*)((char*)d_ws + 12 * 1024 * 1024);  // 10.5 MB
    float2* mlp = (float2*)((char*)d_ws + 23068672);                            // 0.66 MB

    qkv_proj_mfma<<<BB * TT / 128, 256, 0, stream>>>(x, Wk, Wq, Wv, q16, k16, vt16);
    attn_mfma<<<8 * 80, 256, 0, stream>>>(q16, k16, vt16, Opart, mlp, out);
    combine<<<8 * 24, 256, 0, stream>>>(Opart, mlp, out);
}